// Round 3
// baseline (459.257 us; speedup 1.0000x reference)
//
#include <hip/hip_runtime.h>
#include <math.h>

#define HD 64
#define WPB 4

typedef unsigned short u16;
typedef unsigned int u32;
typedef __attribute__((ext_vector_type(8))) short short8;
typedef __attribute__((ext_vector_type(4))) float f32x4;

__device__ __forceinline__ u16 f2bf(float f) {
  return (u16)((__float_as_uint(f) + 0x8000u) >> 16);  // round-half-up
}
__device__ __forceinline__ float bf2f(u16 x) {
  return __uint_as_float(((u32)x) << 16);
}
__device__ __forceinline__ int uswz(int row, int col) {
  return ((row << 6) | col) ^ ((row & 7) << 3);
}
// wave-local LDS fence: plain lgkm wait, NO sched_barrier (lets global loads
// and VALU overlap; all DS ops are compiler-visible so ordering is sound).
__device__ __forceinline__ void fence() {
  asm volatile("s_waitcnt lgkmcnt(0)" ::: "memory");
}
__device__ __forceinline__ float rlane(float v, int l) {
  return __uint_as_float(__builtin_amdgcn_readlane(__float_as_uint(v), l));
}

template <int MT>
__device__ __forceinline__ void zacc(f32x4 (*acc)[4]) {
#pragma unroll
  for (int a_ = 0; a_ < MT; ++a_)
#pragma unroll
    for (int b_ = 0; b_ < 4; ++b_) {
      f32x4 z = {0.0f, 0.0f, 0.0f, 0.0f};
      acc[a_][b_] = z;
    }
}

// acc += A(LDS swizzled bf16 [<=25][64], rows clamped to RMAX) @ W([n][k] bf16)
template <int MT, int RMAX>
__device__ __forceinline__ void mm(const u16* A_, const u16* __restrict__ WT,
                                   f32x4 (*acc)[4], int lane) {
  const int c15 = lane & 15;
  const int q8 = (lane >> 4) << 3;
  short8 b[4][2];
#pragma unroll
  for (int nt = 0; nt < 4; ++nt)
#pragma unroll
    for (int s = 0; s < 2; ++s)
      b[nt][s] = *reinterpret_cast<const short8*>(WT + (nt * 16 + c15) * 64 + s * 32 + q8);
#pragma unroll
  for (int mt = 0; mt < MT; ++mt) {
    int row = mt * 16 + c15;
    row = row > RMAX ? RMAX : row;  // clamp: padded rows duplicate RMAX (outputs >=25 unused)
    const int idx = ((row << 6) | q8) ^ ((row & 7) << 3);
    const short8 a0 = *reinterpret_cast<const short8*>(A_ + idx);
    const short8 a1 = *reinterpret_cast<const short8*>(A_ + (idx ^ 32));
#pragma unroll
    for (int nt = 0; nt < 4; ++nt)
      acc[mt][nt] = __builtin_amdgcn_mfma_f32_16x16x32_bf16(a0, b[nt][0], acc[mt][nt], 0, 0, 0);
#pragma unroll
    for (int nt = 0; nt < 4; ++nt)
      acc[mt][nt] = __builtin_amdgcn_mfma_f32_16x16x32_bf16(a1, b[nt][1], acc[mt][nt], 0, 0, 0);
  }
}

// kemb matmul: A = EF [25][32] plain bf16 (cols 12..31 zero), W = [64][32]
__device__ __forceinline__ void mmEF(const u16* A_, const u16* __restrict__ WT,
                                     f32x4 (*acc)[4], int lane) {
  const int c15 = lane & 15;
  const int q8 = (lane >> 4) << 3;
  short8 b[4];
#pragma unroll
  for (int nt = 0; nt < 4; ++nt)
    b[nt] = *reinterpret_cast<const short8*>(WT + (nt * 16 + c15) * 32 + q8);
#pragma unroll
  for (int mt = 0; mt < 2; ++mt) {
    int row = mt * 16 + c15;
    row = row > 24 ? 24 : row;
    const short8 a = *reinterpret_cast<const short8*>(A_ + row * 32 + q8);
#pragma unroll
    for (int nt = 0; nt < 4; ++nt)
      acc[mt][nt] = __builtin_amdgcn_mfma_f32_16x16x32_bf16(a, b[nt], acc[mt][nt], 0, 0, 0);
  }
}

template <int MT, bool RELU>
__device__ __forceinline__ void epi(u16* D_, f32x4 (*acc)[4],
                                    const float* __restrict__ bias, int lane,
                                    int rowoff, int rowlim) {
  const int c15 = lane & 15, q = lane >> 4;
#pragma unroll
  for (int nt = 0; nt < 4; ++nt) {
    const int col = nt * 16 + c15;
    const float bb = bias ? bias[col] : 0.0f;
#pragma unroll
    for (int mt = 0; mt < MT; ++mt)
#pragma unroll
      for (int i = 0; i < 4; ++i) {
        const int row = mt * 16 + q * 4 + i;
        if (row < rowlim) {
          float v = acc[mt][nt][i] + bb;
          if (RELU) v = fmaxf(v, 0.0f);
          D_[uswz(row + rowoff, col)] = f2bf(v);
        }
      }
  }
}

// ---- pre-pass: pack weights to bf16 transposed [n][k] ----
__global__ __launch_bounds__(256) void prepack(
    const float* __restrict__ br_w1, const float* __restrict__ br_w2,
    const float* __restrict__ out_w, const float* __restrict__ e_w1,
    const float* __restrict__ e_w2, const float* __restrict__ c_w1,
    const float* __restrict__ v_w1, const float* __restrict__ n_w1,
    const float* __restrict__ n_w2, const float* __restrict__ ic_wef,
    u16* __restrict__ W) {
  const int m = blockIdx.x;
  if (m == 16) {  // ic_wef^T, K padded 12->32 with zeros
    for (int e = threadIdx.x; e < 2048; e += blockDim.x) {
      const int n = e >> 5, k = e & 31;
      W[16 * 4096 + e] = (k < 12) ? f2bf(ic_wef[k * 64 + n]) : (u16)0;
    }
    return;
  }
  const float* src;
  switch (m) {
    case 0: src = br_w1; break;
    case 1: src = br_w1 + 4096; break;
    case 2: src = br_w1 + 8192; break;
    case 3: src = br_w2; break;
    case 4: src = br_w2 + 4096; break;
    case 5: src = br_w2 + 8192; break;
    case 6: src = out_w; break;
    case 7: src = e_w1; break;             // h[row]
    case 8: src = e_w1 + 64 * 64; break;   // h[col]
    case 9: src = e_w1 + 129 * 64; break;  // kemb
    case 10: src = e_w2; break;
    case 11: src = c_w1; break;
    case 12: src = v_w1; break;
    case 13: src = n_w1; break;            // h half
    case 14: src = n_w1 + 64 * 64; break;  // nagg half
    default: src = n_w2; break;
  }
  u16* dst = W + m * 4096;
  for (int e = threadIdx.x; e < 4096; e += blockDim.x) {
    const int n = e >> 6, k = e & 63;
    dst[e] = f2bf(src[k * 64 + n]);
  }
}

__global__ __launch_bounds__(64 * WPB, 4) void egcl_mfma(
    const float* __restrict__ gh, const float* __restrict__ gcoord,
    const float* __restrict__ gvel, const u16* __restrict__ W,
    const float* __restrict__ e_w1, const float* __restrict__ e_b1,
    const float* __restrict__ e_b2,
    const float* __restrict__ n_b1, const float* __restrict__ n_b2,
    const float* __restrict__ c_b1, const float* __restrict__ c_w2,
    const float* __restrict__ v_b1, const float* __restrict__ v_w2,
    const float* __restrict__ v_b2,
    const float* __restrict__ ic_pat,
    const float* __restrict__ br_b1, const float* __restrict__ br_b2,
    const float* __restrict__ out_b,
    float* __restrict__ hout, float* __restrict__ cout, int B) {
  // 5120 u16 per wave: H[5][64]@0, K@320, T@1920, U@3520 (each [25][64] swz)
  __shared__ __align__(16) u16 arena[WPB][5120];

  const int t = threadIdx.x & 63;
  const int wv = threadIdx.x >> 6;
  const int g = blockIdx.x * WPB + wv;
  if (g >= B) return;  // waves independent; no block barriers anywhere

  u16* H_ = &arena[wv][0];
  u16* K_ = &arena[wv][320];
  u16* T_ = &arena[wv][1920];
  u16* U_ = &arena[wv][3520];
  u16* EFa = T_;  // EF lives in T before T's first matmul use: [25][32] plain
  const int c15 = t & 15, q = t >> 4;
#define WT(m) (W + (m) * 4096)

  // ---------------- R0: inputs ----------------
  float scvreg = 0.0f;
  if (t < 15) scvreg = gcoord[g * 15 + t];
  else if (t >= 16 && t < 31) scvreg = gvel[g * 15 + (t - 16)];

#pragma unroll
  for (int i = 0; i < 5; ++i) H_[uswz(i, t)] = f2bf(gh[(g * 5 + i) * HD + t]);

  // zero EF cols 12..31 (rows 0..24): 250 u32 slots
#pragma unroll
  for (int z = 0; z < 4; ++z) {
    const int e = t + z * 64;
    if (e < 250) {
      const int row = e / 10, cc = 12 + (e % 10) * 2;
      *reinterpret_cast<u32*>(EFa + row * 32 + cc) = 0u;
    }
  }

  float sqcc = 0.0f;  // squared coord-dist for this lane's tuple (radial)
  if (t < 25) {
    const int ti = t / 5, tj = t % 5;
    const float cix = __shfl(scvreg, ti * 3 + 0, 64), ciy = __shfl(scvreg, ti * 3 + 1, 64), ciz = __shfl(scvreg, ti * 3 + 2, 64);
    const float cjx = __shfl(scvreg, tj * 3 + 0, 64), cjy = __shfl(scvreg, tj * 3 + 1, 64), cjz = __shfl(scvreg, tj * 3 + 2, 64);
    const float vix = __shfl(scvreg, 16 + ti * 3 + 0, 64), viy = __shfl(scvreg, 16 + ti * 3 + 1, 64), viz = __shfl(scvreg, 16 + ti * 3 + 2, 64);
    const float vjx = __shfl(scvreg, 16 + tj * 3 + 0, 64), vjy = __shfl(scvreg, 16 + tj * 3 + 1, 64), vjz = __shfl(scvreg, 16 + tj * 3 + 2, 64);
    {
      const float dx = cix - cjx, dy = ciy - cjy, dz = ciz - cjz;
      sqcc = dx * dx + dy * dy + dz * dz;
    }
    auto sd = [](float sq) { return (sq > 0.0f) ? sqrtf(sq) : 0.0f; };
    const float dcc = sd(sqcc);
    float sq2;
    {
      const float dx = vix - vjx, dy = viy - vjy, dz = viz - vjz;
      sq2 = dx * dx + dy * dy + dz * dz;
    }
    const float dvv = sd(sq2);
    {
      const float dx = cix - vjx, dy = ciy - vjy, dz = ciz - vjz;
      sq2 = dx * dx + dy * dy + dz * dz;
    }
    const float dcv = sd(sq2);
    {
      const float dx = cjx - vix, dy = cjy - viy, dz = cjz - viz;
      sq2 = dx * dx + dy * dy + dz * dz;
    }
    const float dvc = sd(sq2);
    auto rbf3 = [&](float d, int base) {
      const float cut = (d <= 10.0f) ? (0.5f * (cosf(d * 0.31415926535897931f) + 1.0f)) : 0.0f;
      const float e = expf(-0.5f * d);
      const float u0 = e - 4.5399929762484854e-05f;
      const float u1 = e - 0.50002270f;
      const float u2 = e - 1.0f;
      const float BETA = 2.2502043f;
      EFa[t * 32 + base + 0] = f2bf((cut * expf(-BETA * u0 * u0) - 0.05f) * (1.0f / 0.15f));
      EFa[t * 32 + base + 1] = f2bf((cut * expf(-BETA * u1 * u1) - 0.05f) * (1.0f / 0.15f));
      EFa[t * 32 + base + 2] = f2bf((cut * expf(-BETA * u2 * u2) - 0.05f) * (1.0f / 0.15f));
    };
    rbf3(dcc, 0);
    rbf3(dvv, 3);
    rbf3(dcv, 6);
    rbf3(dvc, 9);
  }
  fence();

  f32x4 acc2[2][4];
  f32x4 acc1[1][4];

  // ---------------- R1: kemb = (ef @ ic_wef) * ic_pat[pattern] -> K ----------
  zacc<2>(acc2);
  mmEF(EFa, WT(16), acc2, t);
  {
#pragma unroll
    for (int nt = 0; nt < 4; ++nt) {
      const int col = nt * 16 + c15;
      const float p1 = ic_pat[64 + col], p2 = ic_pat[128 + col];
#pragma unroll
      for (int mt = 0; mt < 2; ++mt)
#pragma unroll
        for (int i = 0; i < 4; ++i) {
          const int row = mt * 16 + q * 4 + i;
          if (row < 25) {
            const bool diag = (row % 6) == 0;  // tuples 0,6,12,18,24
            K_[uswz(row, col)] = f2bf(acc2[mt][nt][i] * (diag ? p2 : p1));
          }
        }
    }
  }
  fence();

  // ---------------- branches k0, k1 ----------------
  zacc<2>(acc2); mm<2, 24>(K_, WT(1), acc2, t); epi<2, true>(T_, acc2, br_b1 + 64, t, 0, 25); fence();
  zacc<2>(acc2); mm<2, 24>(T_, WT(4), acc2, t); epi<2, true>(U_, acc2, br_b2 + 64, t, 0, 25); fence();
  zacc<2>(acc2); mm<2, 24>(K_, WT(2), acc2, t); epi<2, true>(T_, acc2, br_b1 + 128, t, 0, 25); fence();
  zacc<2>(acc2); mm<2, 24>(T_, WT(5), acc2, t);
  fence();  // T A-reads done before same-buffer frag write
  epi<2, true>(T_, acc2, br_b2 + 128, t, 0, 25);
  fence();

  // ---------------- einsum (col mode) + sm L1 ----------------
  {
    float k0c[25], k1c[25];
#pragma unroll
    for (int p = 0; p < 25; ++p) {
      k0c[p] = bf2f(U_[uswz(p, t)]);
      k1c[p] = bf2f(T_[uswz(p, t)]);
    }
    float mu[25];
#pragma unroll
    for (int i = 0; i < 5; ++i)
#pragma unroll
      for (int k = 0; k < 5; ++k) {
        float m = 0.0f;
#pragma unroll
        for (int j = 0; j < 5; ++j) m = fmaf(k0c[i * 5 + j], k1c[j * 5 + k], m);
        mu[i * 5 + k] = m;
      }
#pragma unroll
    for (int p = 0; p < 25; ++p) U_[uswz(p, t)] = f2bf(mu[p]);  // same-addr as k0c reads
  }
  zacc<2>(acc2); mm<2, 24>(K_, WT(0), acc2, t);
  fence();  // mu writes + T col reads done
  epi<2, true>(T_, acc2, br_b1, t, 0, 25);
  fence();

  // ---------------- sm L2, z = relu(sm+b)*mult -> T ----------------
  zacc<2>(acc2); mm<2, 24>(T_, WT(3), acc2, t);
  fence();  // T A-reads done before overwrite
  {
#pragma unroll
    for (int nt = 0; nt < 4; ++nt) {
      const int col = nt * 16 + c15;
      const float bb = br_b2[col];
#pragma unroll
      for (int mt = 0; mt < 2; ++mt)
#pragma unroll
        for (int i = 0; i < 4; ++i) {
          const int row = mt * 16 + q * 4 + i;
          if (row < 25) {
            const int ix = uswz(row, col);
            const float sv = fmaxf(acc2[mt][nt][i] + bb, 0.0f);
            T_[ix] = f2bf(sv * bf2f(U_[ix]));
          }
        }
    }
  }
  fence();

  // ---------------- out_w + residual into K ----------------
  zacc<2>(acc2); mm<2, 24>(T_, WT(6), acc2, t);
  {
#pragma unroll
    for (int nt = 0; nt < 4; ++nt) {
      const int col = nt * 16 + c15;
      const float ob = out_b[col];
#pragma unroll
      for (int mt = 0; mt < 2; ++mt)
#pragma unroll
        for (int i = 0; i < 4; ++i) {
          const int row = mt * 16 + q * 4 + i;
          if (row < 25) {
            const int ix = uswz(row, col);
            K_[ix] = f2bf(fmaxf(acc2[mt][nt][i] + ob, 0.0f) + bf2f(K_[ix]));
          }
        }
    }
  }
  fence();

  // ---------------- edge: accC -> T ----------------
  zacc<2>(acc2); mm<2, 24>(K_, WT(9), acc2, t); epi<2, false>(T_, acc2, nullptr, t, 0, 25);
  fence();

  // ---------------- accA/accB -> U rows 0-4 / 8-12, v-model in regs --------
  float vm[5];
  {
    zacc<1>(acc1); mm<1, 4>(H_, WT(7), acc1, t); epi<1, false>(U_, acc1, nullptr, t, 0, 5);
    zacc<1>(acc1); mm<1, 4>(H_, WT(8), acc1, t); epi<1, false>(U_, acc1, nullptr, t, 8, 5);
    zacc<1>(acc1); mm<1, 4>(H_, WT(12), acc1, t);
    float sv[4];
#pragma unroll
    for (int i = 0; i < 4; ++i) {
      float s = 0.0f;
#pragma unroll
      for (int nt = 0; nt < 4; ++nt) {
        const int col = nt * 16 + c15;
        s += fmaxf(acc1[0][nt][i] + v_b1[col], 0.0f) * v_w2[col];
      }
      s += __shfl_xor(s, 1, 64);
      s += __shfl_xor(s, 2, 64);
      s += __shfl_xor(s, 4, 64);
      s += __shfl_xor(s, 8, 64);
      sv[i] = s;
    }
    const float vb2 = v_b2[0];
#pragma unroll
    for (int i = 0; i < 5; ++i) vm[i] = rlane(sv[i & 3], (i >> 2) << 4) + vb2;
  }
  fence();

  // ---------------- edge assembly (col mode) ----------------
  {
    float cc25[25];
#pragma unroll
    for (int p = 0; p < 25; ++p) cc25[p] = bf2f(T_[uswz(p, t)]);
    float aAc[5], aBc[5];
#pragma unroll
    for (int i = 0; i < 5; ++i) {
      aAc[i] = bf2f(U_[uswz(i, t)]);
      aBc[i] = bf2f(U_[uswz(8 + i, t)]);
    }
    const float eb1v = e_b1[t];
    const float wradv = e_w1[128 * HD + t];
    float ec[20];
#pragma unroll
    for (int p = 0; p < 20; ++p) {
      const int i = p >> 2, jj = p & 3;
      const int j = jj + (jj >= i ? 1 : 0);
      const float radial = rlane(sqcc, i * 5 + j);
      ec[p] = fmaxf(aAc[i] + aBc[j] + radial * wradv + cc25[i * 5 + j] + eb1v, 0.0f);
    }
    fence();  // T/U col reads done before T overwrite
#pragma unroll
    for (int p = 0; p < 20; ++p) T_[uswz(p, t)] = f2bf(ec[p]);
  }
  fence();

  // ---------------- e_w2 -> edge_feat in U ----------------
  zacc<2>(acc2); mm<2, 24>(T_, WT(10), acc2, t); epi<2, true>(U_, acc2, e_b2, t, 0, 25);
  fence();

  // ---------------- nagg -> K rows 0-4; c-model ----------------
  float cm[20];
  {
#pragma unroll
    for (int i = 0; i < 5; ++i) {
      float na = 0.0f;
#pragma unroll
      for (int jj = 0; jj < 4; ++jj) na += bf2f(U_[uswz(4 * i + jj, t)]);
      K_[uswz(i, t)] = f2bf(na);
    }
    zacc<2>(acc2); mm<2, 24>(U_, WT(11), acc2, t);
    float sv[2][4];
#pragma unroll
    for (int mt = 0; mt < 2; ++mt)
#pragma unroll
      for (int i = 0; i < 4; ++i) {
        float s = 0.0f;
#pragma unroll
        for (int nt = 0; nt < 4; ++nt) {
          const int col = nt * 16 + c15;
          s += fmaxf(acc2[mt][nt][i] + c_b1[col], 0.0f) * c_w2[col];
        }
        s += __shfl_xor(s, 1, 64);
        s += __shfl_xor(s, 2, 64);
        s += __shfl_xor(s, 4, 64);
        s += __shfl_xor(s, 8, 64);
        sv[mt][i] = s;
      }
#pragma unroll
    for (int p = 0; p < 20; ++p)
      cm[p] = rlane(sv[p >> 4][p & 3], ((p & 15) >> 2) << 4);
  }
  fence();

  // ---------------- coord output (VALU only) ----------------
  float coutreg = 0.0f;
#pragma unroll
  for (int i = 0; i < 5; ++i) {
#pragma unroll
    for (int d = 0; d < 3; ++d) {
      const float ci = rlane(scvreg, i * 3 + d);
      float s = 0.0f;
#pragma unroll
      for (int jj = 0; jj < 4; ++jj) {
        const int j = jj + (jj >= i ? 1 : 0);
        float tr = (ci - rlane(scvreg, j * 3 + d)) * cm[i * 4 + jj];
        tr = fminf(fmaxf(tr, -100.0f), 100.0f);
        s += tr;
      }
      const float val = ci + 0.25f * s + rlane(scvreg, 16 + i * 3 + d) * vm[i];
      if (t == i * 3 + d) coutreg = val;
    }
  }

  // ---------------- node model ----------------
  zacc<1>(acc1);
  mm<1, 4>(H_, WT(13), acc1, t);
  mm<1, 4>(K_, WT(14), acc1, t);
  epi<1, true>(T_, acc1, n_b1, t, 0, 5);
  fence();
  zacc<1>(acc1); mm<1, 4>(T_, WT(15), acc1, t);
  {
#pragma unroll
    for (int nt = 0; nt < 4; ++nt) {
      const int col = nt * 16 + c15;
      const float nb = n_b2[col];
#pragma unroll
      for (int i = 0; i < 4; ++i) {
        const int row = q * 4 + i;
        if (row < 5) {
          const size_t ix = (size_t)(g * 5 + row) * HD + col;
          hout[ix] = gh[ix] + acc1[0][nt][i] + nb;
        }
      }
    }
  }
  if (t < 15) cout[g * 15 + t] = coutreg;
#undef WT
}

extern "C" void kernel_launch(void* const* d_in, const int* in_sizes, int n_in,
                              void* d_out, int out_size, void* d_ws, size_t ws_size,
                              hipStream_t stream) {
  if (n_in < 27) return;
  const float* gh    = (const float*)d_in[0];
  const float* coord = (const float*)d_in[1];
  const float* vel   = (const float*)d_in[2];
  const float* e_w1 = (const float*)d_in[4];
  const float* e_b1 = (const float*)d_in[5];
  const float* e_w2 = (const float*)d_in[6];
  const float* e_b2 = (const float*)d_in[7];
  const float* n_w1 = (const float*)d_in[8];
  const float* n_b1 = (const float*)d_in[9];
  const float* n_w2 = (const float*)d_in[10];
  const float* n_b2 = (const float*)d_in[11];
  const float* c_w1 = (const float*)d_in[12];
  const float* c_b1 = (const float*)d_in[13];
  const float* c_w2 = (const float*)d_in[14];
  const float* v_w1 = (const float*)d_in[15];
  const float* v_b1 = (const float*)d_in[16];
  const float* v_w2 = (const float*)d_in[17];
  const float* v_b2 = (const float*)d_in[18];
  const float* ic_wef = (const float*)d_in[19];
  const float* ic_pat = (const float*)d_in[20];
  const float* br_w1 = (const float*)d_in[21];
  const float* br_b1 = (const float*)d_in[22];
  const float* br_w2 = (const float*)d_in[23];
  const float* br_b2 = (const float*)d_in[24];
  const float* out_w = (const float*)d_in[25];
  const float* out_b = (const float*)d_in[26];

  const int N = in_sizes[0] / HD;  // 100000
  const int B = N / 5;             // 20000 graphs
  float* hout = (float*)d_out;
  float* cout = (float*)d_out + (size_t)N * HD;
  u16* W = (u16*)d_ws;  // 16*4096 + 2048 u16 = 135168 B

  prepack<<<17, 256, 0, stream>>>(br_w1, br_w2, out_w, e_w1, e_w2, c_w1, v_w1,
                                  n_w1, n_w2, ic_wef, W);

  const int blocks = (B + WPB - 1) / WPB;
  egcl_mfma<<<blocks, 64 * WPB, 0, stream>>>(
      gh, coord, vel, W, e_w1, e_b1, e_b2, n_b1, n_b2, c_b1, c_w2, v_b1, v_w2,
      v_b2, ic_pat, br_b1, br_b2, out_b, hout, cout, B);
}

// Round 4
// 371.160 us; speedup vs baseline: 1.2374x; 1.2374x over previous
//
#include <hip/hip_runtime.h>
#include <math.h>

#define HD 64
#define WPB 2

typedef unsigned short u16;
typedef unsigned int u32;
typedef __attribute__((ext_vector_type(8))) short short8;
typedef __attribute__((ext_vector_type(4))) float f32x4;

__device__ __forceinline__ u16 f2bf(float f) {
  return (u16)((__float_as_uint(f) + 0x8000u) >> 16);  // round-half-up
}
__device__ __forceinline__ float bf2f(u16 x) {
  return __uint_as_float(((u32)x) << 16);
}
__device__ __forceinline__ int uswz(int row, int col) {
  return ((row << 6) | col) ^ ((row & 7) << 3);
}
__device__ __forceinline__ float rlane(float v, int l) {
  return __uint_as_float(__builtin_amdgcn_readlane(__float_as_uint(v), l));
}

// NOTE: no explicit LDS fences anywhere. All LDS traffic is wave-private and
// compiler-visible: the DS pipe executes a wave's LDS ops in issue order
// (same property that makes counted lgkmcnt pipelining sound), the compiler
// preserves program order for may-alias LDS accesses and auto-inserts
// data-return waits. This leaves one big scheduling region so B-fragment
// global loads and epilogues overlap across phases.

template <int MT>
__device__ __forceinline__ void zacc(f32x4 (*acc)[4]) {
#pragma unroll
  for (int a_ = 0; a_ < MT; ++a_)
#pragma unroll
    for (int b_ = 0; b_ < 4; ++b_) {
      f32x4 z = {0.0f, 0.0f, 0.0f, 0.0f};
      acc[a_][b_] = z;
    }
}

// acc += A(LDS swizzled bf16 [<=25][64], rows clamped to RMAX) @ W([n][k] bf16)
template <int MT, int RMAX>
__device__ __forceinline__ void mm(const u16* A_, const u16* __restrict__ WT,
                                   f32x4 (*acc)[4], int lane) {
  const int c15 = lane & 15;
  const int q8 = (lane >> 4) << 3;
  short8 b[4][2];
#pragma unroll
  for (int nt = 0; nt < 4; ++nt)
#pragma unroll
    for (int s = 0; s < 2; ++s)
      b[nt][s] = *reinterpret_cast<const short8*>(WT + (nt * 16 + c15) * 64 + s * 32 + q8);
#pragma unroll
  for (int mt = 0; mt < MT; ++mt) {
    int row = mt * 16 + c15;
    row = row > RMAX ? RMAX : row;  // clamp: padded rows duplicate RMAX
    const int idx = ((row << 6) | q8) ^ ((row & 7) << 3);
    const short8 a0 = *reinterpret_cast<const short8*>(A_ + idx);
    const short8 a1 = *reinterpret_cast<const short8*>(A_ + (idx ^ 32));
#pragma unroll
    for (int nt = 0; nt < 4; ++nt)
      acc[mt][nt] = __builtin_amdgcn_mfma_f32_16x16x32_bf16(a0, b[nt][0], acc[mt][nt], 0, 0, 0);
#pragma unroll
    for (int nt = 0; nt < 4; ++nt)
      acc[mt][nt] = __builtin_amdgcn_mfma_f32_16x16x32_bf16(a1, b[nt][1], acc[mt][nt], 0, 0, 0);
  }
}

// kemb matmul: A = EF [25][32] plain bf16 (cols 12..31 zero), W = [64][32]
__device__ __forceinline__ void mmEF(const u16* A_, const u16* __restrict__ WT,
                                     f32x4 (*acc)[4], int lane) {
  const int c15 = lane & 15;
  const int q8 = (lane >> 4) << 3;
  short8 b[4];
#pragma unroll
  for (int nt = 0; nt < 4; ++nt)
    b[nt] = *reinterpret_cast<const short8*>(WT + (nt * 16 + c15) * 32 + q8);
#pragma unroll
  for (int mt = 0; mt < 2; ++mt) {
    int row = mt * 16 + c15;
    row = row > 24 ? 24 : row;
    const short8 a = *reinterpret_cast<const short8*>(A_ + row * 32 + q8);
#pragma unroll
    for (int nt = 0; nt < 4; ++nt)
      acc[mt][nt] = __builtin_amdgcn_mfma_f32_16x16x32_bf16(a, b[nt], acc[mt][nt], 0, 0, 0);
  }
}

template <int MT, bool RELU>
__device__ __forceinline__ void epi(u16* D_, f32x4 (*acc)[4],
                                    const float* __restrict__ bias, int lane,
                                    int rowoff, int rowlim) {
  const int c15 = lane & 15, q = lane >> 4;
#pragma unroll
  for (int nt = 0; nt < 4; ++nt) {
    const int col = nt * 16 + c15;
    const float bb = bias ? bias[col] : 0.0f;
#pragma unroll
    for (int mt = 0; mt < MT; ++mt)
#pragma unroll
      for (int i = 0; i < 4; ++i) {
        const int row = mt * 16 + q * 4 + i;
        if (row < rowlim) {
          float v = acc[mt][nt][i] + bb;
          if (RELU) v = fmaxf(v, 0.0f);
          D_[uswz(row + rowoff, col)] = f2bf(v);
        }
      }
  }
}

// ---- pre-pass: pack weights to bf16 transposed [n][k] ----
__global__ __launch_bounds__(256) void prepack(
    const float* __restrict__ br_w1, const float* __restrict__ br_w2,
    const float* __restrict__ out_w, const float* __restrict__ e_w1,
    const float* __restrict__ e_w2, const float* __restrict__ c_w1,
    const float* __restrict__ v_w1, const float* __restrict__ n_w1,
    const float* __restrict__ n_w2, const float* __restrict__ ic_wef,
    u16* __restrict__ W) {
  const int m = blockIdx.x;
  if (m == 16) {  // ic_wef^T, K padded 12->32 with zeros
    for (int e = threadIdx.x; e < 2048; e += blockDim.x) {
      const int n = e >> 5, k = e & 31;
      W[16 * 4096 + e] = (k < 12) ? f2bf(ic_wef[k * 64 + n]) : (u16)0;
    }
    return;
  }
  const float* src;
  switch (m) {
    case 0: src = br_w1; break;
    case 1: src = br_w1 + 4096; break;
    case 2: src = br_w1 + 8192; break;
    case 3: src = br_w2; break;
    case 4: src = br_w2 + 4096; break;
    case 5: src = br_w2 + 8192; break;
    case 6: src = out_w; break;
    case 7: src = e_w1; break;             // h[row]
    case 8: src = e_w1 + 64 * 64; break;   // h[col]
    case 9: src = e_w1 + 129 * 64; break;  // kemb
    case 10: src = e_w2; break;
    case 11: src = c_w1; break;
    case 12: src = v_w1; break;
    case 13: src = n_w1; break;            // h half
    case 14: src = n_w1 + 64 * 64; break;  // nagg half
    default: src = n_w2; break;
  }
  u16* dst = W + m * 4096;
  for (int e = threadIdx.x; e < 4096; e += blockDim.x) {
    const int n = e >> 6, k = e & 63;
    dst[e] = f2bf(src[k * 64 + n]);
  }
}

__global__ __launch_bounds__(64 * WPB, 3) void egcl_mfma(
    const float* __restrict__ gh, const float* __restrict__ gcoord,
    const float* __restrict__ gvel, const u16* __restrict__ W,
    const float* __restrict__ e_w1, const float* __restrict__ e_b1,
    const float* __restrict__ e_b2,
    const float* __restrict__ n_b1, const float* __restrict__ n_b2,
    const float* __restrict__ c_b1, const float* __restrict__ c_w2,
    const float* __restrict__ v_b1, const float* __restrict__ v_w2,
    const float* __restrict__ v_b2,
    const float* __restrict__ ic_pat,
    const float* __restrict__ br_b1, const float* __restrict__ br_b2,
    const float* __restrict__ out_b,
    float* __restrict__ hout, float* __restrict__ cout, int B) {
  // 5120 u16 per wave: H[5][64]@0, K@320, T@1920, U@3520 (each [25][64] swz)
  __shared__ __align__(16) u16 arena[WPB][5120];

  const int t = threadIdx.x & 63;
  const int wv = threadIdx.x >> 6;
  const int g = blockIdx.x * WPB + wv;
  if (g >= B) return;  // waves independent; no block barriers anywhere

  u16* H_ = &arena[wv][0];
  u16* K_ = &arena[wv][320];
  u16* T_ = &arena[wv][1920];
  u16* U_ = &arena[wv][3520];
  u16* EFa = T_;  // EF lives in T before T's first matmul use: [25][32] plain
  const int c15 = t & 15, q = t >> 4;
#define WT(m) (W + (m) * 4096)

  // ---------------- R0: inputs ----------------
  float scvreg = 0.0f;
  if (t < 15) scvreg = gcoord[g * 15 + t];
  else if (t >= 16 && t < 31) scvreg = gvel[g * 15 + (t - 16)];

#pragma unroll
  for (int i = 0; i < 5; ++i) H_[uswz(i, t)] = f2bf(gh[(g * 5 + i) * HD + t]);

  // zero EF cols 12..31 (rows 0..24): 250 u32 slots
#pragma unroll
  for (int z = 0; z < 4; ++z) {
    const int e = t + z * 64;
    if (e < 250) {
      const int row = e / 10, cc = 12 + (e % 10) * 2;
      *reinterpret_cast<u32*>(EFa + row * 32 + cc) = 0u;
    }
  }

  float sqcc = 0.0f;  // squared coord-dist for this lane's tuple (radial)
  if (t < 25) {
    const int ti = t / 5, tj = t % 5;
    const float cix = __shfl(scvreg, ti * 3 + 0, 64), ciy = __shfl(scvreg, ti * 3 + 1, 64), ciz = __shfl(scvreg, ti * 3 + 2, 64);
    const float cjx = __shfl(scvreg, tj * 3 + 0, 64), cjy = __shfl(scvreg, tj * 3 + 1, 64), cjz = __shfl(scvreg, tj * 3 + 2, 64);
    const float vix = __shfl(scvreg, 16 + ti * 3 + 0, 64), viy = __shfl(scvreg, 16 + ti * 3 + 1, 64), viz = __shfl(scvreg, 16 + ti * 3 + 2, 64);
    const float vjx = __shfl(scvreg, 16 + tj * 3 + 0, 64), vjy = __shfl(scvreg, 16 + tj * 3 + 1, 64), vjz = __shfl(scvreg, 16 + tj * 3 + 2, 64);
    {
      const float dx = cix - cjx, dy = ciy - cjy, dz = ciz - cjz;
      sqcc = dx * dx + dy * dy + dz * dz;
    }
    auto sd = [](float sq) { return (sq > 0.0f) ? sqrtf(sq) : 0.0f; };
    const float dcc = sd(sqcc);
    float sq2;
    {
      const float dx = vix - vjx, dy = viy - vjy, dz = viz - vjz;
      sq2 = dx * dx + dy * dy + dz * dz;
    }
    const float dvv = sd(sq2);
    {
      const float dx = cix - vjx, dy = ciy - vjy, dz = ciz - vjz;
      sq2 = dx * dx + dy * dy + dz * dz;
    }
    const float dcv = sd(sq2);
    {
      const float dx = cjx - vix, dy = cjy - viy, dz = cjz - viz;
      sq2 = dx * dx + dy * dy + dz * dz;
    }
    const float dvc = sd(sq2);
    auto rbf3 = [&](float d, int base) {
      const float cut = (d <= 10.0f) ? (0.5f * (cosf(d * 0.31415926535897931f) + 1.0f)) : 0.0f;
      const float e = expf(-0.5f * d);
      const float u0 = e - 4.5399929762484854e-05f;
      const float u1 = e - 0.50002270f;
      const float u2 = e - 1.0f;
      const float BETA = 2.2502043f;
      EFa[t * 32 + base + 0] = f2bf((cut * expf(-BETA * u0 * u0) - 0.05f) * (1.0f / 0.15f));
      EFa[t * 32 + base + 1] = f2bf((cut * expf(-BETA * u1 * u1) - 0.05f) * (1.0f / 0.15f));
      EFa[t * 32 + base + 2] = f2bf((cut * expf(-BETA * u2 * u2) - 0.05f) * (1.0f / 0.15f));
    };
    rbf3(dcc, 0);
    rbf3(dvv, 3);
    rbf3(dcv, 6);
    rbf3(dvc, 9);
  }

  f32x4 acc2[2][4];
  f32x4 acc1[1][4];

  // ---------------- R1: kemb = (ef @ ic_wef) * ic_pat[pattern] -> K ----------
  zacc<2>(acc2);
  mmEF(EFa, WT(16), acc2, t);
  {
#pragma unroll
    for (int nt = 0; nt < 4; ++nt) {
      const int col = nt * 16 + c15;
      const float p1 = ic_pat[64 + col], p2 = ic_pat[128 + col];
#pragma unroll
      for (int mt = 0; mt < 2; ++mt)
#pragma unroll
        for (int i = 0; i < 4; ++i) {
          const int row = mt * 16 + q * 4 + i;
          if (row < 25) {
            const bool diag = (row % 6) == 0;  // tuples 0,6,12,18,24
            K_[uswz(row, col)] = f2bf(acc2[mt][nt][i] * (diag ? p2 : p1));
          }
        }
    }
  }

  // ---------------- branches k0, k1 ----------------
  zacc<2>(acc2); mm<2, 24>(K_, WT(1), acc2, t); epi<2, true>(T_, acc2, br_b1 + 64, t, 0, 25);
  zacc<2>(acc2); mm<2, 24>(T_, WT(4), acc2, t); epi<2, true>(U_, acc2, br_b2 + 64, t, 0, 25);
  zacc<2>(acc2); mm<2, 24>(K_, WT(2), acc2, t); epi<2, true>(T_, acc2, br_b1 + 128, t, 0, 25);
  zacc<2>(acc2); mm<2, 24>(T_, WT(5), acc2, t); epi<2, true>(T_, acc2, br_b2 + 128, t, 0, 25);

  // ---------------- einsum (col mode, j-outer to limit live regs) ----------
  {
    float mu[25];
#pragma unroll
    for (int p = 0; p < 25; ++p) mu[p] = 0.0f;
#pragma unroll
    for (int j = 0; j < 5; ++j) {
      float k1r[5], k0c[5];
#pragma unroll
      for (int k = 0; k < 5; ++k) k1r[k] = bf2f(T_[uswz(j * 5 + k, t)]);
#pragma unroll
      for (int i = 0; i < 5; ++i) k0c[i] = bf2f(U_[uswz(i * 5 + j, t)]);
#pragma unroll
      for (int i = 0; i < 5; ++i)
#pragma unroll
        for (int k = 0; k < 5; ++k) mu[i * 5 + k] = fmaf(k0c[i], k1r[k], mu[i * 5 + k]);
    }
#pragma unroll
    for (int p = 0; p < 25; ++p) U_[uswz(p, t)] = f2bf(mu[p]);
  }

  // ---------------- sm L1 / L2, z = relu(sm+b)*mult -> T ----------------
  zacc<2>(acc2); mm<2, 24>(K_, WT(0), acc2, t); epi<2, true>(T_, acc2, br_b1, t, 0, 25);
  zacc<2>(acc2); mm<2, 24>(T_, WT(3), acc2, t);
  {
#pragma unroll
    for (int nt = 0; nt < 4; ++nt) {
      const int col = nt * 16 + c15;
      const float bb = br_b2[col];
#pragma unroll
      for (int mt = 0; mt < 2; ++mt)
#pragma unroll
        for (int i = 0; i < 4; ++i) {
          const int row = mt * 16 + q * 4 + i;
          if (row < 25) {
            const int ix = uswz(row, col);
            const float sv = fmaxf(acc2[mt][nt][i] + bb, 0.0f);
            T_[ix] = f2bf(sv * bf2f(U_[ix]));
          }
        }
    }
  }

  // ---------------- out_w + residual into K ----------------
  zacc<2>(acc2); mm<2, 24>(T_, WT(6), acc2, t);
  {
#pragma unroll
    for (int nt = 0; nt < 4; ++nt) {
      const int col = nt * 16 + c15;
      const float ob = out_b[col];
#pragma unroll
      for (int mt = 0; mt < 2; ++mt)
#pragma unroll
        for (int i = 0; i < 4; ++i) {
          const int row = mt * 16 + q * 4 + i;
          if (row < 25) {
            const int ix = uswz(row, col);
            K_[ix] = f2bf(fmaxf(acc2[mt][nt][i] + ob, 0.0f) + bf2f(K_[ix]));
          }
        }
    }
  }

  // ---------------- edge: accC -> T ----------------
  zacc<2>(acc2); mm<2, 24>(K_, WT(9), acc2, t); epi<2, false>(T_, acc2, nullptr, t, 0, 25);

  // ---------------- accA/accB -> U rows 0-4 / 8-12, v-model in regs --------
  float vm[5];
  {
    zacc<1>(acc1); mm<1, 4>(H_, WT(7), acc1, t); epi<1, false>(U_, acc1, nullptr, t, 0, 5);
    zacc<1>(acc1); mm<1, 4>(H_, WT(8), acc1, t); epi<1, false>(U_, acc1, nullptr, t, 8, 5);
    zacc<1>(acc1); mm<1, 4>(H_, WT(12), acc1, t);
    float sv[4];
#pragma unroll
    for (int i = 0; i < 4; ++i) {
      float s = 0.0f;
#pragma unroll
      for (int nt = 0; nt < 4; ++nt) {
        const int col = nt * 16 + c15;
        s += fmaxf(acc1[0][nt][i] + v_b1[col], 0.0f) * v_w2[col];
      }
      s += __shfl_xor(s, 1, 64);
      s += __shfl_xor(s, 2, 64);
      s += __shfl_xor(s, 4, 64);
      s += __shfl_xor(s, 8, 64);
      sv[i] = s;
    }
    const float vb2 = v_b2[0];
#pragma unroll
    for (int i = 0; i < 5; ++i) vm[i] = rlane(sv[i & 3], (i >> 2) << 4) + vb2;
  }

  // ---------------- edge assembly (col mode, inline accC reads) ----------
  {
    float aAc[5], aBc[5];
#pragma unroll
    for (int i = 0; i < 5; ++i) {
      aAc[i] = bf2f(U_[uswz(i, t)]);
      aBc[i] = bf2f(U_[uswz(8 + i, t)]);
    }
    const float eb1v = e_b1[t];
    const float wradv = e_w1[128 * HD + t];
    float ec[20];
#pragma unroll
    for (int p = 0; p < 20; ++p) {
      const int i = p >> 2, jj = p & 3;
      const int j = jj + (jj >= i ? 1 : 0);
      const float radial = rlane(sqcc, i * 5 + j);
      const float cc = bf2f(T_[uswz(i * 5 + j, t)]);
      ec[p] = fmaxf(aAc[i] + aBc[j] + radial * wradv + cc + eb1v, 0.0f);
    }
#pragma unroll
    for (int p = 0; p < 20; ++p) T_[uswz(p, t)] = f2bf(ec[p]);
  }

  // ---------------- e_w2 -> edge_feat in U ----------------
  zacc<2>(acc2); mm<2, 24>(T_, WT(10), acc2, t); epi<2, true>(U_, acc2, e_b2, t, 0, 25);

  // ---------------- nagg -> K rows 0-4; c-model ----------------
  float cm[20];
  {
#pragma unroll
    for (int i = 0; i < 5; ++i) {
      float na = 0.0f;
#pragma unroll
      for (int jj = 0; jj < 4; ++jj) na += bf2f(U_[uswz(4 * i + jj, t)]);
      K_[uswz(i, t)] = f2bf(na);
    }
    zacc<2>(acc2); mm<2, 24>(U_, WT(11), acc2, t);
    float sv[2][4];
#pragma unroll
    for (int mt = 0; mt < 2; ++mt)
#pragma unroll
      for (int i = 0; i < 4; ++i) {
        float s = 0.0f;
#pragma unroll
        for (int nt = 0; nt < 4; ++nt) {
          const int col = nt * 16 + c15;
          s += fmaxf(acc2[mt][nt][i] + c_b1[col], 0.0f) * c_w2[col];
        }
        s += __shfl_xor(s, 1, 64);
        s += __shfl_xor(s, 2, 64);
        s += __shfl_xor(s, 4, 64);
        s += __shfl_xor(s, 8, 64);
        sv[mt][i] = s;
      }
#pragma unroll
    for (int p = 0; p < 20; ++p)
      cm[p] = rlane(sv[p >> 4][p & 3], ((p & 15) >> 2) << 4);
  }

  // ---------------- coord output (VALU only) ----------------
  float coutreg = 0.0f;
#pragma unroll
  for (int i = 0; i < 5; ++i) {
#pragma unroll
    for (int d = 0; d < 3; ++d) {
      const float ci = rlane(scvreg, i * 3 + d);
      float s = 0.0f;
#pragma unroll
      for (int jj = 0; jj < 4; ++jj) {
        const int j = jj + (jj >= i ? 1 : 0);
        float tr = (ci - rlane(scvreg, j * 3 + d)) * cm[i * 4 + jj];
        tr = fminf(fmaxf(tr, -100.0f), 100.0f);
        s += tr;
      }
      const float val = ci + 0.25f * s + rlane(scvreg, 16 + i * 3 + d) * vm[i];
      if (t == i * 3 + d) coutreg = val;
    }
  }

  // ---------------- node model ----------------
  zacc<1>(acc1);
  mm<1, 4>(H_, WT(13), acc1, t);
  mm<1, 4>(K_, WT(14), acc1, t);
  epi<1, true>(T_, acc1, n_b1, t, 0, 5);
  zacc<1>(acc1); mm<1, 4>(T_, WT(15), acc1, t);
  {
#pragma unroll
    for (int nt = 0; nt < 4; ++nt) {
      const int col = nt * 16 + c15;
      const float nb = n_b2[col];
#pragma unroll
      for (int i = 0; i < 4; ++i) {
        const int row = q * 4 + i;
        if (row < 5) {
          const size_t ix = (size_t)(g * 5 + row) * HD + col;
          hout[ix] = gh[ix] + acc1[0][nt][i] + nb;
        }
      }
    }
  }
  if (t < 15) cout[g * 15 + t] = coutreg;
#undef WT
}

extern "C" void kernel_launch(void* const* d_in, const int* in_sizes, int n_in,
                              void* d_out, int out_size, void* d_ws, size_t ws_size,
                              hipStream_t stream) {
  if (n_in < 27) return;
  const float* gh    = (const float*)d_in[0];
  const float* coord = (const float*)d_in[1];
  const float* vel   = (const float*)d_in[2];
  const float* e_w1 = (const float*)d_in[4];
  const float* e_b1 = (const float*)d_in[5];
  const float* e_w2 = (const float*)d_in[6];
  const float* e_b2 = (const float*)d_in[7];
  const float* n_w1 = (const float*)d_in[8];
  const float* n_b1 = (const float*)d_in[9];
  const float* n_w2 = (const float*)d_in[10];
  const float* n_b2 = (const float*)d_in[11];
  const float* c_w1 = (const float*)d_in[12];
  const float* c_b1 = (const float*)d_in[13];
  const float* c_w2 = (const float*)d_in[14];
  const float* v_w1 = (const float*)d_in[15];
  const float* v_b1 = (const float*)d_in[16];
  const float* v_w2 = (const float*)d_in[17];
  const float* v_b2 = (const float*)d_in[18];
  const float* ic_wef = (const float*)d_in[19];
  const float* ic_pat = (const float*)d_in[20];
  const float* br_w1 = (const float*)d_in[21];
  const float* br_b1 = (const float*)d_in[22];
  const float* br_w2 = (const float*)d_in[23];
  const float* br_b2 = (const float*)d_in[24];
  const float* out_w = (const float*)d_in[25];
  const float* out_b = (const float*)d_in[26];

  const int N = in_sizes[0] / HD;  // 100000
  const int B = N / 5;             // 20000 graphs
  float* hout = (float*)d_out;
  float* cout = (float*)d_out + (size_t)N * HD;
  u16* W = (u16*)d_ws;  // 16*4096 + 2048 u16 = 135168 B

  prepack<<<17, 256, 0, stream>>>(br_w1, br_w2, out_w, e_w1, e_w2, c_w1, v_w1,
                                  n_w1, n_w2, ic_wef, W);

  const int blocks = (B + WPB - 1) / WPB;
  egcl_mfma<<<blocks, 64 * WPB, 0, stream>>>(
      gh, coord, vel, W, e_w1, e_b1, e_b2, n_b1, n_b2, c_b1, c_w2, v_b1, v_w2,
      v_b2, ic_pat, br_b1, br_b2, out_b, hout, cout, B);
}